// Round 2
// baseline (1501.621 us; speedup 1.0000x reference)
//
#include <hip/hip_runtime.h>
#include <hip/hip_cooperative_groups.h>

namespace cg = cooperative_groups;

#define DD 128          // feature dim
#define KC 32           // k-chunk in gemm
#define MT 64           // rows per block in gemm
#define ELLC 128        // ELL row capacity (deg ~ Poisson(32); max over 20K nodes ~65)
#define NBMAX 320       // max dst-buckets (64 nodes each)
#define ACAP 2304       // bucket capacity: mean 2045, sigma ~45 -> +5.7 sigma
#define AEPW 4096       // edges per phase-A workgroup
#define MEGA_GRID 1024  // 4 blocks/CU x 256 CU (launch_bounds(256,4); LDS 25.6KB -> 4/CU)

__device__ __forceinline__ unsigned f2bf_rne(float f) {
    unsigned u = __float_as_uint(f);
    u += 0x7fffu + ((u >> 16) & 1u);
    return u >> 16;
}

// ---------------- GEMM body ----------------
// xt = x @ W.T + b (fp32, possibly IN-PLACE on x: each block reads only its own
// 64 rows and writes them in the epilogue after all k-chunks are consumed),
// plus packed-bf16 copy xtb laid out as TWO 64-feature planes of (PS=N+1) rows
// x 128 B each (row N of each plane is a permanently-zero sentinel row).
// NOTE: x/xt deliberately NOT __restrict__ (they alias for layers 2,3).
__device__ __forceinline__ void gemm_body(float (*Xs)[MT + 4], float (*Ws)[DD + 4],
                                          const float* x,
                                          const float* __restrict__ W,
                                          const float* __restrict__ b,
                                          float* xt,
                                          unsigned* __restrict__ xtb, int M, int PS, int blk) {
    const int tid  = threadIdx.x;       // 0..255
    const int cg_  = tid & 15;          // cols cg*8 .. cg*8+7
    const int rg   = tid >> 4;          // rows rg*4 .. rg*4+3
    const int row0 = blk * MT;

    float acc[4][8];
#pragma unroll
    for (int i = 0; i < 4; ++i)
#pragma unroll
        for (int j = 0; j < 8; ++j) acc[i][j] = 0.0f;

    for (int kc = 0; kc < DD; kc += KC) {
#pragma unroll
        for (int it = 0; it < 2; ++it) {
            int idx = tid + it * 256;   // 0..511
            int r = idx >> 3, kq = idx & 7;
            int gr = row0 + r;
            float4 v = make_float4(0.f, 0.f, 0.f, 0.f);
            if (gr < M) v = *(const float4*)&x[gr * DD + kc + kq * 4];
            Xs[kq * 4 + 0][r] = v.x; Xs[kq * 4 + 1][r] = v.y;
            Xs[kq * 4 + 2][r] = v.z; Xs[kq * 4 + 3][r] = v.w;
        }
#pragma unroll
        for (int it = 0; it < 4; ++it) {
            int idx = tid + it * 256;   // 0..1023
            int o = idx >> 3, kq = idx & 7;
            float4 v = *(const float4*)&W[o * DD + kc + kq * 4];
            Ws[kq * 4 + 0][o] = v.x; Ws[kq * 4 + 1][o] = v.y;
            Ws[kq * 4 + 2][o] = v.z; Ws[kq * 4 + 3][o] = v.w;
        }
        __syncthreads();

#pragma unroll 8
        for (int k = 0; k < KC; ++k) {
            float4 xv = *(const float4*)&Xs[k][rg * 4];
            float4 w0 = *(const float4*)&Ws[k][cg_ * 8];
            float4 w1 = *(const float4*)&Ws[k][cg_ * 8 + 4];
            float xr[4] = {xv.x, xv.y, xv.z, xv.w};
            float wc[8] = {w0.x, w0.y, w0.z, w0.w, w1.x, w1.y, w1.z, w1.w};
#pragma unroll
            for (int i = 0; i < 4; ++i)
#pragma unroll
                for (int j = 0; j < 8; ++j) acc[i][j] += xr[i] * wc[j];
        }
        __syncthreads();
    }

    float4 b0 = *(const float4*)&b[cg_ * 8];
    float4 b1 = *(const float4*)&b[cg_ * 8 + 4];
    float bb[8] = {b0.x, b0.y, b0.z, b0.w, b1.x, b1.y, b1.z, b1.w};
#pragma unroll
    for (int i = 0; i < 4; ++i) {
        int gr = row0 + rg * 4 + i;
        if (gr < M) {
            float v[8];
#pragma unroll
            for (int j = 0; j < 8; ++j) v[j] = acc[i][j] + bb[j];
            *(float4*)&xt[gr * DD + cg_ * 8]     = make_float4(v[0], v[1], v[2], v[3]);
            *(float4*)&xt[gr * DD + cg_ * 8 + 4] = make_float4(v[4], v[5], v[6], v[7]);
            uint4 p;
            p.x = f2bf_rne(v[0]) | (f2bf_rne(v[1]) << 16);
            p.y = f2bf_rne(v[2]) | (f2bf_rne(v[3]) << 16);
            p.z = f2bf_rne(v[4]) | (f2bf_rne(v[5]) << 16);
            p.w = f2bf_rne(v[6]) | (f2bf_rne(v[7]) << 16);
            unsigned* xp = xtb + (size_t)(cg_ >> 3) * ((size_t)PS * 32)
                               + (size_t)gr * 32 + ((cg_ & 7) << 2);
            *(uint4*)xp = p;
        }
    }
}

// ---------------- Phase-A binning body ----------------
__device__ __forceinline__ void binA_body(int* hist, int* basec, int* cur,
                                          const int* __restrict__ src,
                                          const int* __restrict__ dst,
                                          int* __restrict__ bucket_count,
                                          unsigned* __restrict__ bstore,
                                          int E, int NB, int blk) {
    const int tid = threadIdx.x;
    for (int i = tid; i < NB; i += 256) hist[i] = 0;
    __syncthreads();

    int dv[16], sv[16];
    const int ebase = blk * AEPW;
#pragma unroll
    for (int r = 0; r < 4; ++r) {
        int e = ebase + r * 1024 + tid * 4;
        if (e + 4 <= E) {
            int4 d4 = *(const int4*)&dst[e];
            int4 s4 = *(const int4*)&src[e];
            dv[r*4+0] = d4.x; dv[r*4+1] = d4.y; dv[r*4+2] = d4.z; dv[r*4+3] = d4.w;
            sv[r*4+0] = s4.x; sv[r*4+1] = s4.y; sv[r*4+2] = s4.z; sv[r*4+3] = s4.w;
        } else {
#pragma unroll
            for (int q = 0; q < 4; ++q) {
                int ee = e + q;
                if (ee < E) { dv[r*4+q] = dst[ee]; sv[r*4+q] = src[ee]; }
                else        { dv[r*4+q] = -1;      sv[r*4+q] = 0; }
            }
        }
    }
#pragma unroll
    for (int i = 0; i < 16; ++i)
        if (dv[i] >= 0) atomicAdd(&hist[dv[i] >> 6], 1);
    __syncthreads();

    for (int bk = tid; bk < NB; bk += 256) {
        int h = hist[bk];
        basec[bk] = h ? atomicAdd(&bucket_count[bk], h) : 0;
        cur[bk] = 0;
    }
    __syncthreads();

#pragma unroll
    for (int i = 0; i < 16; ++i) {
        if (dv[i] >= 0) {
            int bk = dv[i] >> 6;
            int pos = basec[bk] + atomicAdd(&cur[bk], 1);
            if (pos < ACAP)
                bstore[bk * ACAP + pos] = ((unsigned)(dv[i] & 63) << 16) | (unsigned)sv[i];
        }
    }
}

// ---------------- Phase-B ELL body ----------------
__device__ __forceinline__ void ell_body(int* c64, const unsigned* __restrict__ bstore,
                                         const int* __restrict__ bucket_count,
                                         unsigned short* __restrict__ colell,
                                         int* __restrict__ deg,
                                         unsigned* __restrict__ xtb,
                                         int PS, int N, int bk) {
    for (int i = threadIdx.x; i < 64; i += 256) c64[i] = 0;
    __syncthreads();
    int cnt = bucket_count[bk];
    if (cnt > ACAP) cnt = ACAP;
    for (int i = threadIdx.x; i < cnt; i += 256) {
        unsigned code = bstore[bk * ACAP + i];
        int local = (int)(code >> 16);
        int s     = (int)(code & 0xffffu);
        int p = atomicAdd(&c64[local], 1);
        if (p < ELLC)
            colell[((((bk << 6) + local)) << 7) + p] = (unsigned short)s;
    }
    __syncthreads();
    if (threadIdx.x < 64) {
        int node = (bk << 6) + threadIdx.x;
        if (node < N) {
            int d = c64[threadIdx.x];
            deg[node] = d;
            int stored = d < ELLC ? d : ELLC;
            int padded = (stored + 15) & ~15;
            if (padded > ELLC) padded = ELLC;
            unsigned short* row = colell + ((size_t)node << 7);
            for (int p2 = stored; p2 < padded; ++p2) row[p2] = (unsigned short)N;
        }
    }
    if (bk == 0 && threadIdx.x >= 64 && threadIdx.x < 80) {
        int i  = threadIdx.x - 64;      // 0..15
        int pl = i >> 3;                // plane
        int j  = i & 7;                 // uint4 index within row
        *(uint4*)&xtb[((size_t)pl * PS + (size_t)N) * 32 + (size_t)j * 4] =
            make_uint4(0u, 0u, 0u, 0u);
    }
}

// ---------------- aggregate body (one node-plane pair per wave call) ----------------
// out[n,f] = relu( (sum_e bf16(xt[col[e],f])) / deg[n] ) + xt[n,f]
// Lanes: h=lane&15 carries features 4h..4h+3 of the plane, q=lane>>4 carries
// edge slot -> each uint2 gather fetches FOUR edges' 128-B plane rows.
// ELL rows padded to multiples of 16 edges with sentinel N (zero row).
__device__ __forceinline__ void agg_one(const uint2* __restrict__ xtb2, const float* xt,
                                        const unsigned short* __restrict__ colell,
                                        const int* __restrict__ deg, float* out,
                                        int PS, int node, int plane, int lane) {
    const int h = lane & 15;
    const int q = lane >> 4;

    const uint2* __restrict__ xl = xtb2 + (size_t)plane * ((size_t)PS << 4) + h;
    const unsigned short* __restrict__ crow = colell + ((size_t)node << 7);
    const int cnt = deg[node];                        // wave-uniform (true degree)
    const int cl  = cnt < ELLC ? cnt : ELLC;          // stored edges

    float a0 = 0.f, a1 = 0.f, a2 = 0.f, a3 = 0.f;

#define GATH(u_, j_) { int s_ = __shfl(myidx, ((t + (j_)) << 2) | q, 64); \
                       (u_)[j_] = xl[(size_t)s_ << 4]; }
#define UNPK(u_, j_) { a0 += __uint_as_float((u_)[j_].x << 16); \
                       a1 += __uint_as_float((u_)[j_].x & 0xffff0000u); \
                       a2 += __uint_as_float((u_)[j_].y << 16); \
                       a3 += __uint_as_float((u_)[j_].y & 0xffff0000u); }

    for (int base = 0; base < cl; base += 64) {
        const int rem = cl - base;
        const int c = rem < 64 ? rem : 64;
        const int myidx = (int)crow[base + lane];     // coalesced ushort (padded rows)
        const int cq = ((c + 15) >> 4) << 2;          // quads, rounded to 4 (16 edges)
        int t = 0;
        for (; t + 8 <= cq; t += 8) {                 // flight of 8 instrs = 32 edges
            uint2 u[8];
            GATH(u,0) GATH(u,1) GATH(u,2) GATH(u,3)
            GATH(u,4) GATH(u,5) GATH(u,6) GATH(u,7)
            UNPK(u,0) UNPK(u,1) UNPK(u,2) UNPK(u,3)
            UNPK(u,4) UNPK(u,5) UNPK(u,6) UNPK(u,7)
        }
        if (t < cq) {                                 // exactly 4 quads = 16 edges
            uint2 u[4];
            GATH(u,0) GATH(u,1) GATH(u,2) GATH(u,3)
            UNPK(u,0) UNPK(u,1) UNPK(u,2) UNPK(u,3)
        }
    }
#undef GATH
#undef UNPK

    a0 += __shfl_down(a0, 32, 64);
    a1 += __shfl_down(a1, 32, 64);
    a2 += __shfl_down(a2, 32, 64);
    a3 += __shfl_down(a3, 32, 64);
    a0 += __shfl_down(a0, 16, 64);
    a1 += __shfl_down(a1, 16, 64);
    a2 += __shfl_down(a2, 16, 64);
    a3 += __shfl_down(a3, 16, 64);

    if (q == 0) {
        const float di = (cnt > 0) ? (1.0f / (float)cnt) : 0.0f;
        float4 t4 = ((const float4*)xt)[(size_t)node * 32 + plane * 16 + h];
        float4 o;
        o.x = fmaxf(a0 * di, 0.f) + t4.x;
        o.y = fmaxf(a1 * di, 0.f) + t4.y;
        o.z = fmaxf(a2 * di, 0.f) + t4.z;
        o.w = fmaxf(a3 * di, 0.f) + t4.w;
        ((float4*)out)[(size_t)node * 32 + plane * 16 + h] = o;
    }
}

// ================= cooperative mega-kernel =================
// All 8 former dispatches as phases of ONE kernel with grid-wide barriers.
// Grid MUST be fully co-resident: 1024 blocks @ launch_bounds(256,4)
// (25.6KB LDS + <=128 VGPR -> 4 blocks/CU on 256 CUs).
__global__ __launch_bounds__(256, 4) void gcn_mega(
    const float* x,
    const float* __restrict__ W1, const float* __restrict__ b1,
    const float* __restrict__ W2, const float* __restrict__ b2,
    const float* __restrict__ W3, const float* __restrict__ b3,
    float* xbuf, unsigned* __restrict__ xtb,
    const int* __restrict__ src, const int* __restrict__ dst,
    int* __restrict__ bucket_count, unsigned* __restrict__ bstore,
    unsigned short* __restrict__ colell, int* __restrict__ deg,
    int N, int E, int PS, int NB, int PA, int GB)
{
    __shared__ __align__(16) char smem[(KC * (MT + 4) + KC * (DD + 4)) * sizeof(float)];
    float (*Xs)[MT + 4] = (float (*)[MT + 4])smem;
    float (*Ws)[DD + 4] = (float (*)[DD + 4])(smem + KC * (MT + 4) * sizeof(float));
    int* hist  = (int*)smem;            // phase-A view (3.8KB)
    int* basec = hist + NBMAX;
    int* cur   = basec + NBMAX;
    int* c64   = (int*)smem;            // phase-B view (256B)

    cg::grid_group grid = cg::this_grid();
    const int nb = (int)gridDim.x;
    const int wave = threadIdx.x >> 6;
    const int lane = threadIdx.x & 63;

    // P0: zero bucket_count
    for (int i = (int)blockIdx.x * 256 + threadIdx.x; i < NB; i += nb * 256)
        bucket_count[i] = 0;
    __threadfence();
    grid.sync();

    // P1: edge binning (units 0..PA-1) + layer-1 GEMM (units PA..PA+GB-1)
    for (int u = blockIdx.x; u < PA + GB; u += nb) {
        if (u < PA) binA_body(hist, basec, cur, src, dst, bucket_count, bstore, E, NB, u);
        else        gemm_body(Xs, Ws, x, W1, b1, xbuf, xtb, N, PS, u - PA);
        __syncthreads();
    }
    __threadfence();
    grid.sync();

    // P2: ELL build + deg + sentinel rows
    for (int u = blockIdx.x; u < NB; u += nb) {
        ell_body(c64, bstore, bucket_count, colell, deg, xtb, PS, N, u);
        __syncthreads();
    }
    __threadfence();
    grid.sync();

    // P3..P7: agg1, gemm2, agg2, gemm3, agg3
    const uint2* xtb2 = (const uint2*)xtb;
    for (int l = 0; l < 3; ++l) {
        if (l > 0) {
            const float* W = (l == 1) ? W2 : W3;
            const float* b = (l == 1) ? b2 : b3;
            for (int u = blockIdx.x; u < GB; u += nb) {
                gemm_body(Xs, Ws, xbuf, W, b, xbuf, xtb, N, PS, u);
                __syncthreads();
            }
            __threadfence();
            grid.sync();
        }
        // aggregate: one node-plane pair per wave, grid-stride
        for (int p = (int)blockIdx.x * 4 + wave; p < 2 * N; p += nb * 4) {
            int plane = (p >= N) ? 1 : 0;
            int node  = plane ? (p - N) : p;
            agg_one(xtb2, xbuf, colell, deg, xbuf, PS, node, plane, lane);
        }
        if (l < 2) {
            __threadfence();
            grid.sync();
        }
    }
}

// ================= fallback standalone kernels (verified path) =================
__global__ __launch_bounds__(256) void gemm_xwT(const float* x,
                                                const float* __restrict__ W,
                                                const float* __restrict__ b,
                                                float* xt,
                                                unsigned* __restrict__ xtb, int M, int PS) {
    __shared__ float Xs[KC][MT + 4];
    __shared__ float Ws[KC][DD + 4];
    gemm_body(Xs, Ws, x, W, b, xt, xtb, M, PS, blockIdx.x);
}

__global__ __launch_bounds__(256) void gemm1_plus_binA(const float* x,
                                                       const float* __restrict__ W,
                                                       const float* __restrict__ b,
                                                       float* xt,
                                                       unsigned* __restrict__ xtb, int M, int PS,
                                                       const int* __restrict__ src,
                                                       const int* __restrict__ dst,
                                                       int* __restrict__ bucket_count,
                                                       unsigned* __restrict__ bstore,
                                                       int E, int NB, int PA) {
    __shared__ float Xs[KC][MT + 4];
    __shared__ float Ws[KC][DD + 4];
    __shared__ int hist[NBMAX];
    __shared__ int basec[NBMAX];
    __shared__ int cur[NBMAX];
    if ((int)blockIdx.x >= PA) {
        gemm_body(Xs, Ws, x, W, b, xt, xtb, M, PS, blockIdx.x - PA);
        return;
    }
    binA_body(hist, basec, cur, src, dst, bucket_count, bstore, E, NB, blockIdx.x);
}

__global__ __launch_bounds__(256) void ell_build(const unsigned* __restrict__ bstore,
                                                 const int* __restrict__ bucket_count,
                                                 unsigned short* __restrict__ colell,
                                                 int* __restrict__ deg,
                                                 unsigned* __restrict__ xtb,
                                                 int PS, int N) {
    __shared__ int c64[64];
    ell_body(c64, bstore, bucket_count, colell, deg, xtb, PS, N, blockIdx.x);
}

__global__ __launch_bounds__(256) void gcn_aggregate(const uint2* __restrict__ xtb2,
                                                     const float* xt,
                                                     const unsigned short* __restrict__ colell,
                                                     const int* __restrict__ deg,
                                                     float* out, int PS, int N) {
    const int wave  = threadIdx.x >> 6;
    const int lane  = threadIdx.x & 63;
    const int xcd   = blockIdx.x & 7;
    const int plane = xcd >> 2;
    const int widx  = ((blockIdx.x >> 3) << 2) | (xcd & 3);
    const int node  = (widx << 2) | wave;
    if (node >= N) return;
    agg_one(xtb2, xt, colell, deg, out, PS, node, plane, lane);
}

extern "C" void kernel_launch(void* const* d_in, const int* in_sizes, int n_in,
                              void* d_out, int out_size, void* d_ws, size_t ws_size,
                              hipStream_t stream) {
    const float* x  = (const float*)d_in[0];
    const int*   ei = (const int*)d_in[1];      // [2, E] int32
    const float* W1 = (const float*)d_in[2];
    const float* b1 = (const float*)d_in[3];
    const float* W2 = (const float*)d_in[4];
    const float* b2 = (const float*)d_in[5];
    const float* W3 = (const float*)d_in[6];
    const float* b3 = (const float*)d_in[7];

    int N  = in_sizes[0] / DD;     // 20000
    int E  = in_sizes[1] / 2;      // 640000
    int PS = N + 1;                // plane row count (incl. zero sentinel row)

    const int* src = ei;
    const int* dst = ei + E;

    int NB = (N + 63) >> 6;            // 313 buckets
    int PA = (E + AEPW - 1) / AEPW;    // 157 phase-A blocks
    int GB = (N + MT - 1) / MT;        // 313 gemm blocks
    const int SUP = (N + 15) >> 4;     // fallback aggregate supers
    const int AGB = SUP * 8;

    // workspace layout (256B-aligned offsets) — ~13.2 MB total
    char* ws = (char*)d_ws;
    size_t off = 0;
    auto alloc = [&](size_t bytes) {
        void* p = ws + off;
        off += (bytes + 255) & ~(size_t)255;
        return p;
    };
    int*            bucket_count = (int*)alloc((size_t)NB * sizeof(int));
    unsigned*       bstore       = (unsigned*)alloc((size_t)NB * ACAP * sizeof(unsigned));
    unsigned short* colell       = (unsigned short*)alloc((size_t)NB * 64 * ELLC * sizeof(unsigned short));
    int*            deg          = (int*)alloc((size_t)N * sizeof(int));
    unsigned*       xtb          = (unsigned*)alloc((size_t)PS * 256);   // 2 planes x PS x 128 B

    float* xbuf = (float*)d_out;  // fp32 xt lives in d_out (in-place per layer)

    // ---- try single cooperative mega-kernel (all phases, 7 grid syncs) ----
    {
        void* args[] = {
            (void*)&x,  (void*)&W1, (void*)&b1, (void*)&W2, (void*)&b2,
            (void*)&W3, (void*)&b3, (void*)&xbuf, (void*)&xtb,
            (void*)&src, (void*)&dst, (void*)&bucket_count, (void*)&bstore,
            (void*)&colell, (void*)&deg,
            (void*)&N, (void*)&E, (void*)&PS, (void*)&NB, (void*)&PA, (void*)&GB
        };
        hipError_t err = hipLaunchCooperativeKernel((const void*)gcn_mega,
                                                    dim3(MEGA_GRID), dim3(256),
                                                    args, 0, stream);
        if (err == hipSuccess) return;
        (void)hipGetLastError();   // clear error, fall back to multi-kernel path
    }

    // ---- fallback: verified 8-dispatch path ----
    hipMemsetAsync(bucket_count, 0, (size_t)NB * sizeof(int), stream);
    gemm1_plus_binA<<<PA + GB, 256, 0, stream>>>(x, W1, b1, xbuf, xtb, N, PS,
                                                 src, dst, bucket_count, bstore, E, NB, PA);
    ell_build<<<NB, 256, 0, stream>>>(bstore, bucket_count, colell, deg, xtb, PS, N);

    gcn_aggregate<<<AGB, 256, 0, stream>>>((const uint2*)xtb, xbuf, colell, deg, xbuf, PS, N);

    gemm_xwT<<<GB, 256, 0, stream>>>(xbuf, W2, b2, xbuf, xtb, N, PS);
    gcn_aggregate<<<AGB, 256, 0, stream>>>((const uint2*)xtb, xbuf, colell, deg, xbuf, PS, N);

    gemm_xwT<<<GB, 256, 0, stream>>>(xbuf, W3, b3, xbuf, xtb, N, PS);
    gcn_aggregate<<<AGB, 256, 0, stream>>>((const uint2*)xtb, xbuf, colell, deg, xbuf, PS, N);
}

// Round 3
// 347.132 us; speedup vs baseline: 4.3258x; 4.3258x over previous
//
#include <hip/hip_runtime.h>

#define DD 128          // feature dim
#define KC 32           // k-chunk in gemm
#define MT 64           // rows per block in gemm
#define ELLC 128        // ELL row capacity (deg ~ Poisson(32); max over 20K nodes ~65)
#define NBMAX 320       // max dst-buckets (64 nodes each)
#define ACAP 2304       // bucket capacity: mean 2045, sigma ~45 -> +5.7 sigma
#define AEPW 4096       // edges per phase-A workgroup
#define AGB  1024       // aggregate blocks (queue-fed; 4 blocks/CU)
#define QG   16         // nodes grabbed per queue atomic

__device__ __forceinline__ unsigned f2bf_rne(float f) {
    unsigned u = __float_as_uint(f);
    u += 0x7fffu + ((u >> 16) & 1u);
    return u >> 16;
}

// Physical XCD id of the CU this block runs on (gfx940+ HW_REG_XCC_ID = 20).
// If unsupported, returns 0 -> all blocks prefer plane 0, stealing covers the
// rest (correctness never depends on this value).
__device__ __forceinline__ int xcc_id() {
    unsigned v;
    asm volatile("s_getreg_b32 %0, hwreg(20, 0, 4)" : "=s"(v));
    return (int)(v & 7u);
}

// ---------------- GEMM body ----------------
// xt = x @ W.T + b (fp32, possibly IN-PLACE on x: each block reads only its own
// 64 rows and writes them in the epilogue after all k-chunks are consumed),
// plus packed-bf16 copy xtb laid out as TWO 64-feature planes of (PS=N+1) rows
// x 128 B each (each plane = 2.56 MB -> fits a 4-MB per-XCD L2; row N of each
// plane is a permanently-zero sentinel row used by ELL padding).
// NOTE: x/xt deliberately NOT __restrict__ (they alias for layers 2,3).
__device__ __forceinline__ void gemm_body(float (*Xs)[MT + 4], float (*Ws)[DD + 4],
                                          const float* x,
                                          const float* __restrict__ W,
                                          const float* __restrict__ b,
                                          float* xt,
                                          unsigned* __restrict__ xtb, int M, int PS, int blk) {
    const int tid  = threadIdx.x;       // 0..255
    const int cg_  = tid & 15;          // cols cg*8 .. cg*8+7
    const int rg   = tid >> 4;          // rows rg*4 .. rg*4+3
    const int row0 = blk * MT;

    float acc[4][8];
#pragma unroll
    for (int i = 0; i < 4; ++i)
#pragma unroll
        for (int j = 0; j < 8; ++j) acc[i][j] = 0.0f;

    for (int kc = 0; kc < DD; kc += KC) {
#pragma unroll
        for (int it = 0; it < 2; ++it) {
            int idx = tid + it * 256;   // 0..511
            int r = idx >> 3, kq = idx & 7;
            int gr = row0 + r;
            float4 v = make_float4(0.f, 0.f, 0.f, 0.f);
            if (gr < M) v = *(const float4*)&x[gr * DD + kc + kq * 4];
            Xs[kq * 4 + 0][r] = v.x; Xs[kq * 4 + 1][r] = v.y;
            Xs[kq * 4 + 2][r] = v.z; Xs[kq * 4 + 3][r] = v.w;
        }
#pragma unroll
        for (int it = 0; it < 4; ++it) {
            int idx = tid + it * 256;   // 0..1023
            int o = idx >> 3, kq = idx & 7;
            float4 v = *(const float4*)&W[o * DD + kc + kq * 4];
            Ws[kq * 4 + 0][o] = v.x; Ws[kq * 4 + 1][o] = v.y;
            Ws[kq * 4 + 2][o] = v.z; Ws[kq * 4 + 3][o] = v.w;
        }
        __syncthreads();

#pragma unroll 8
        for (int k = 0; k < KC; ++k) {
            float4 xv = *(const float4*)&Xs[k][rg * 4];
            float4 w0 = *(const float4*)&Ws[k][cg_ * 8];
            float4 w1 = *(const float4*)&Ws[k][cg_ * 8 + 4];
            float xr[4] = {xv.x, xv.y, xv.z, xv.w};
            float wc[8] = {w0.x, w0.y, w0.z, w0.w, w1.x, w1.y, w1.z, w1.w};
#pragma unroll
            for (int i = 0; i < 4; ++i)
#pragma unroll
                for (int j = 0; j < 8; ++j) acc[i][j] += xr[i] * wc[j];
        }
        __syncthreads();
    }

    float4 b0 = *(const float4*)&b[cg_ * 8];
    float4 b1 = *(const float4*)&b[cg_ * 8 + 4];
    float bb[8] = {b0.x, b0.y, b0.z, b0.w, b1.x, b1.y, b1.z, b1.w};
#pragma unroll
    for (int i = 0; i < 4; ++i) {
        int gr = row0 + rg * 4 + i;
        if (gr < M) {
            float v[8];
#pragma unroll
            for (int j = 0; j < 8; ++j) v[j] = acc[i][j] + bb[j];
            *(float4*)&xt[gr * DD + cg_ * 8]     = make_float4(v[0], v[1], v[2], v[3]);
            *(float4*)&xt[gr * DD + cg_ * 8 + 4] = make_float4(v[4], v[5], v[6], v[7]);
            uint4 p;
            p.x = f2bf_rne(v[0]) | (f2bf_rne(v[1]) << 16);
            p.y = f2bf_rne(v[2]) | (f2bf_rne(v[3]) << 16);
            p.z = f2bf_rne(v[4]) | (f2bf_rne(v[5]) << 16);
            p.w = f2bf_rne(v[6]) | (f2bf_rne(v[7]) << 16);
            unsigned* xp = xtb + (size_t)(cg_ >> 3) * ((size_t)PS * 32)
                               + (size_t)gr * 32 + ((cg_ & 7) << 2);
            *(uint4*)xp = p;
        }
    }
}

__global__ __launch_bounds__(256) void gemm_xwT(const float* x,
                                                const float* __restrict__ W,
                                                const float* __restrict__ b,
                                                float* xt,
                                                unsigned* __restrict__ xtb, int M, int PS) {
    __shared__ float Xs[KC][MT + 4];
    __shared__ float Ws[KC][DD + 4];
    gemm_body(Xs, Ws, x, W, b, xt, xtb, M, PS, blockIdx.x);
}

// Fused: blocks [0,PA) = Phase-A edge binning (LDS histogram -> few global
// atomics -> semi-coalesced bucket-store writes); blocks [PA,PA+GB) = GEMM-1.
// binA block 0 also zeroes the 6 aggregate queue counters (used 2 dispatches
// later; the K1->K2->agg boundaries make the writes visible).
__global__ __launch_bounds__(256) void gemm1_plus_binA(const float* x,
                                                       const float* __restrict__ W,
                                                       const float* __restrict__ b,
                                                       float* xt,
                                                       unsigned* __restrict__ xtb, int M, int PS,
                                                       const int* __restrict__ src,
                                                       const int* __restrict__ dst,
                                                       int* __restrict__ bucket_count,
                                                       unsigned* __restrict__ bstore,
                                                       int* __restrict__ qc,
                                                       int E, int NB, int PA) {
    __shared__ float Xs[KC][MT + 4];
    __shared__ float Ws[KC][DD + 4];
    __shared__ int hist[NBMAX];
    __shared__ int basec[NBMAX];
    __shared__ int cur[NBMAX];

    if ((int)blockIdx.x >= PA) {
        gemm_body(Xs, Ws, x, W, b, xt, xtb, M, PS, blockIdx.x - PA);
        return;
    }

    const int tid = threadIdx.x;
    if (blockIdx.x == 0 && tid < 6) qc[tid] = 0;   // queue counters for 3 aggregates
    for (int i = tid; i < NB; i += 256) hist[i] = 0;
    __syncthreads();

    // load 16 edges/thread (4 rounds of coalesced int4)
    int dv[16], sv[16];
    const int ebase = blockIdx.x * AEPW;
#pragma unroll
    for (int r = 0; r < 4; ++r) {
        int e = ebase + r * 1024 + tid * 4;
        if (e + 4 <= E) {
            int4 d4 = *(const int4*)&dst[e];
            int4 s4 = *(const int4*)&src[e];
            dv[r*4+0] = d4.x; dv[r*4+1] = d4.y; dv[r*4+2] = d4.z; dv[r*4+3] = d4.w;
            sv[r*4+0] = s4.x; sv[r*4+1] = s4.y; sv[r*4+2] = s4.z; sv[r*4+3] = s4.w;
        } else {
#pragma unroll
            for (int q = 0; q < 4; ++q) {
                int ee = e + q;
                if (ee < E) { dv[r*4+q] = dst[ee]; sv[r*4+q] = src[ee]; }
                else        { dv[r*4+q] = -1;      sv[r*4+q] = 0; }
            }
        }
    }
#pragma unroll
    for (int i = 0; i < 16; ++i)
        if (dv[i] >= 0) atomicAdd(&hist[dv[i] >> 6], 1);
    __syncthreads();

    for (int bk = tid; bk < NB; bk += 256) {
        int h = hist[bk];
        basec[bk] = h ? atomicAdd(&bucket_count[bk], h) : 0;
        cur[bk] = 0;
    }
    __syncthreads();

#pragma unroll
    for (int i = 0; i < 16; ++i) {
        if (dv[i] >= 0) {
            int bk = dv[i] >> 6;
            int pos = basec[bk] + atomicAdd(&cur[bk], 1);
            if (pos < ACAP)
                bstore[bk * ACAP + pos] = ((unsigned)(dv[i] & 63) << 16) | (unsigned)sv[i];
        }
    }
}

// Phase B: one workgroup per bucket. Slot assignment via LDS atomics; colell
// writes stay in a private 16KB region. Emits deg, pads each ELL row to a
// multiple of 4 edges with sentinel index N (the all-zero bf16 row), and
// block 0 writes the zero sentinel rows themselves.
__global__ __launch_bounds__(256) void ell_build(const unsigned* __restrict__ bstore,
                                                 const int* __restrict__ bucket_count,
                                                 unsigned short* __restrict__ colell,
                                                 int* __restrict__ deg,
                                                 unsigned* __restrict__ xtb,
                                                 int PS, int N) {
    __shared__ int c64[64];
    const int bk = blockIdx.x;
    for (int i = threadIdx.x; i < 64; i += 256) c64[i] = 0;
    __syncthreads();
    int cnt = bucket_count[bk];
    if (cnt > ACAP) cnt = ACAP;
    for (int i = threadIdx.x; i < cnt; i += 256) {
        unsigned code = bstore[bk * ACAP + i];
        int local = (int)(code >> 16);
        int s     = (int)(code & 0xffffu);
        int p = atomicAdd(&c64[local], 1);
        if (p < ELLC)
            colell[((((bk << 6) + local)) << 7) + p] = (unsigned short)s;
    }
    __syncthreads();
    if (threadIdx.x < 64) {
        int node = (bk << 6) + threadIdx.x;
        if (node < N) {
            int d = c64[threadIdx.x];
            deg[node] = d;
            int stored = d < ELLC ? d : ELLC;
            int padded = (stored + 3) & ~3;          // pad to 4-edge quads
            if (padded > ELLC) padded = ELLC;
            unsigned short* row = colell + ((size_t)node << 7);
            for (int p2 = stored; p2 < padded; ++p2) row[p2] = (unsigned short)N;
        }
    }
    if (bk == 0 && threadIdx.x >= 64 && threadIdx.x < 80) {
        int i  = threadIdx.x - 64;      // 0..15
        int pl = i >> 3;                // plane
        int j  = i & 7;                 // uint4 index within row
        *(uint4*)&xtb[((size_t)pl * PS + (size_t)N) * 32 + (size_t)j * 4] =
            make_uint4(0u, 0u, 0u, 0u);
    }
}

// ---------------- aggregate body (one node-plane pair per wave call) ----------------
// out[n,f] = relu( (sum_e bf16(xt[col[e],f])) / deg[n] ) + xt[n,f]
// Lanes: h=lane&15 carries features 4h..4h+3 of the plane, q=lane>>4 carries
// edge slot -> each uint2 gather fetches FOUR edges' 128-B plane rows.
// ELL rows padded to multiples of 4 edges with sentinel N (zero row).
__device__ __forceinline__ void agg_one(const uint2* __restrict__ xtb2, const float* xt,
                                        const unsigned short* __restrict__ colell,
                                        const int* __restrict__ deg, float* out,
                                        int PS, int node, int plane, int lane) {
    const int h = lane & 15;
    const int q = lane >> 4;

    const uint2* __restrict__ xl = xtb2 + (size_t)plane * ((size_t)PS << 4) + h;
    const unsigned short* __restrict__ crow = colell + ((size_t)node << 7);
    const int cnt = deg[node];                        // wave-uniform (true degree)
    const int cl  = cnt < ELLC ? cnt : ELLC;          // stored edges

    float a0 = 0.f, a1 = 0.f, a2 = 0.f, a3 = 0.f;

#define GATH(u_, j_) { int s_ = __shfl(myidx, ((t + (j_)) << 2) | q, 64); \
                       (u_)[j_] = xl[(size_t)s_ << 4]; }
#define UNPK(u_, j_) { a0 += __uint_as_float((u_)[j_].x << 16); \
                       a1 += __uint_as_float((u_)[j_].x & 0xffff0000u); \
                       a2 += __uint_as_float((u_)[j_].y << 16); \
                       a3 += __uint_as_float((u_)[j_].y & 0xffff0000u); }

    for (int base = 0; base < cl; base += 64) {
        const int rem = cl - base;
        const int c = rem < 64 ? rem : 64;
        const int myidx = (int)crow[base + lane];     // coalesced ushort (padded rows)
        const int cq = (c + 3) >> 2;                  // 4-edge quads (row padded to 4)
        int t = 0;
        for (; t + 8 <= cq; t += 8) {                 // flight of 8 instrs = 32 edges
            uint2 u[8];
            GATH(u,0) GATH(u,1) GATH(u,2) GATH(u,3)
            GATH(u,4) GATH(u,5) GATH(u,6) GATH(u,7)
            UNPK(u,0) UNPK(u,1) UNPK(u,2) UNPK(u,3)
            UNPK(u,4) UNPK(u,5) UNPK(u,6) UNPK(u,7)
        }
        for (; t < cq; ++t) {                         // tail quads (1 instr = 4 edges)
            uint2 u1[1];
            GATH(u1,0) UNPK(u1,0)
        }
    }
#undef GATH
#undef UNPK

    a0 += __shfl_down(a0, 32, 64);
    a1 += __shfl_down(a1, 32, 64);
    a2 += __shfl_down(a2, 32, 64);
    a3 += __shfl_down(a3, 32, 64);
    a0 += __shfl_down(a0, 16, 64);
    a1 += __shfl_down(a1, 16, 64);
    a2 += __shfl_down(a2, 16, 64);
    a3 += __shfl_down(a3, 16, 64);

    if (q == 0) {
        const float di = (cnt > 0) ? (1.0f / (float)cnt) : 0.0f;
        float4 t4 = ((const float4*)xt)[(size_t)node * 32 + plane * 16 + h];
        float4 o;
        o.x = fmaxf(a0 * di, 0.f) + t4.x;
        o.y = fmaxf(a1 * di, 0.f) + t4.y;
        o.z = fmaxf(a2 * di, 0.f) + t4.z;
        o.w = fmaxf(a3 * di, 0.f) + t4.w;
        ((float4*)out)[(size_t)node * 32 + plane * 16 + h] = o;
    }
}

// XCD-pinned, queue-fed aggregate. Each block reads its PHYSICAL XCD id and
// works the plane matching it (XCD 0-3 -> plane 0, 4-7 -> plane 1) so every
// gather targets a 2.56-MB table resident in that XCD's own 4-MB L2 —
// independent of any blockIdx->XCD mapping assumption. Pass 2 steals the
// other plane's remaining work (correctness for any XCD distribution; no-op
// when the queues drain evenly).
__global__ __launch_bounds__(256) void gcn_aggregate_q(const uint2* __restrict__ xtb2,
                                                       const float* xt,
                                                       const unsigned short* __restrict__ colell,
                                                       const int* __restrict__ deg,
                                                       float* out,
                                                       int* __restrict__ qc,   // [2] counters
                                                       int PS, int N) {
    __shared__ int sbase;
    const int wave = threadIdx.x >> 6;
    const int lane = threadIdx.x & 63;
    const int myplane = (xcc_id() >> 2) & 1;

    for (int pass = 0; pass < 2; ++pass) {
        const int plane = myplane ^ pass;
        int* q = qc + plane;
        for (;;) {
            if (threadIdx.x == 0) sbase = atomicAdd(q, QG);
            __syncthreads();
            const int base = sbase;
            __syncthreads();
            if (base >= N) break;
#pragma unroll
            for (int r = 0; r < QG / 4; ++r) {
                int node = base + (r << 2) + wave;
                if (node < N)
                    agg_one(xtb2, xt, colell, deg, out, PS, node, plane, lane);
            }
        }
    }
}

extern "C" void kernel_launch(void* const* d_in, const int* in_sizes, int n_in,
                              void* d_out, int out_size, void* d_ws, size_t ws_size,
                              hipStream_t stream) {
    const float* x  = (const float*)d_in[0];
    const int*   ei = (const int*)d_in[1];      // [2, E] int32
    const float* W1 = (const float*)d_in[2];
    const float* b1 = (const float*)d_in[3];
    const float* W2 = (const float*)d_in[4];
    const float* b2 = (const float*)d_in[5];
    const float* W3 = (const float*)d_in[6];
    const float* b3 = (const float*)d_in[7];

    const int N  = in_sizes[0] / DD;     // 20000
    const int E  = in_sizes[1] / 2;      // 640000
    const int PS = N + 1;                // plane row count (incl. zero sentinel row)

    const int* src = ei;
    const int* dst = ei + E;

    const int NB = (N + 63) >> 6;            // 313 buckets
    const int PA = (E + AEPW - 1) / AEPW;    // 157 phase-A blocks
    const int GB = (N + MT - 1) / MT;        // 313 gemm blocks

    // workspace layout (256B-aligned offsets) — ~13.2 MB total
    char* ws = (char*)d_ws;
    size_t off = 0;
    auto alloc = [&](size_t bytes) {
        void* p = ws + off;
        off += (bytes + 255) & ~(size_t)255;
        return p;
    };
    int*            bucket_count = (int*)alloc((size_t)NB * sizeof(int));
    unsigned*       bstore       = (unsigned*)alloc((size_t)NB * ACAP * sizeof(unsigned));
    unsigned short* colell       = (unsigned short*)alloc((size_t)NB * 64 * ELLC * sizeof(unsigned short));
    int*            deg          = (int*)alloc((size_t)N * sizeof(int));
    unsigned*       xtb          = (unsigned*)alloc((size_t)PS * 256);   // 2 planes x PS x 128 B
    int*            qc           = (int*)alloc(6 * sizeof(int));         // 3 aggs x 2 plane queues

    float* xbuf = (float*)d_out;  // fp32 xt lives in d_out (in-place per layer)

    hipMemsetAsync(bucket_count, 0, (size_t)NB * sizeof(int), stream);
    // K1: Phase-A binning (+ queue-counter zeroing) + layer-1 GEMM
    gemm1_plus_binA<<<PA + GB, 256, 0, stream>>>(x, W1, b1, xbuf, xtb, N, PS,
                                                 src, dst, bucket_count, bstore, qc, E, NB, PA);
    // K2: Phase-B ELL build + deg + padding + zero sentinel rows
    ell_build<<<NB, 256, 0, stream>>>(bstore, bucket_count, colell, deg, xtb, PS, N);

    gcn_aggregate_q<<<AGB, 256, 0, stream>>>((const uint2*)xtb, xbuf, colell, deg, xbuf,
                                             qc + 0, PS, N);

    gemm_xwT<<<GB, 256, 0, stream>>>(xbuf, W2, b2, xbuf, xtb, N, PS);
    gcn_aggregate_q<<<AGB, 256, 0, stream>>>((const uint2*)xtb, xbuf, colell, deg, xbuf,
                                             qc + 2, PS, N);

    gemm_xwT<<<GB, 256, 0, stream>>>(xbuf, W3, b3, xbuf, xtb, N, PS);
    gcn_aggregate_q<<<AGB, 256, 0, stream>>>((const uint2*)xtb, xbuf, colell, deg, xbuf,
                                             qc + 4, PS, N);
}

// Round 4
// 226.763 us; speedup vs baseline: 6.6220x; 1.5308x over previous
//
#include <hip/hip_runtime.h>

#define DD 128          // feature dim
#define KC 32           // k-chunk in gemm
#define MT 64           // rows per block in gemm
#define ELLC 128        // ELL row capacity (deg ~ Poisson(32); max over 20K nodes ~65)
#define NBMAX 320       // max dst-buckets (64 nodes each)
#define ACAP 2304       // bucket capacity: mean 2045, sigma ~45 -> +5.7 sigma
#define AEPW 4096       // edges per phase-A workgroup

__device__ __forceinline__ unsigned f2bf_rne(float f) {
    unsigned u = __float_as_uint(f);
    u += 0x7fffu + ((u >> 16) & 1u);
    return u >> 16;
}

// ---------------- GEMM body ----------------
// xt = x @ W.T + b (fp32, possibly IN-PLACE on x: each block reads only its own
// 64 rows and writes them in the epilogue after all k-chunks are consumed),
// plus packed-bf16 copy xtb laid out as TWO 64-feature planes of (PS=N+1) rows
// x 128 B each (row N of each plane is a permanently-zero sentinel row used by
// ELL padding).
// NOTE: x/xt deliberately NOT __restrict__ (they alias for layers 2,3).
__device__ __forceinline__ void gemm_body(float (*Xs)[MT + 4], float (*Ws)[DD + 4],
                                          const float* x,
                                          const float* __restrict__ W,
                                          const float* __restrict__ b,
                                          float* xt,
                                          unsigned* __restrict__ xtb, int M, int PS, int blk) {
    const int tid  = threadIdx.x;       // 0..255
    const int cg_  = tid & 15;          // cols cg*8 .. cg*8+7
    const int rg   = tid >> 4;          // rows rg*4 .. rg*4+3
    const int row0 = blk * MT;

    float acc[4][8];
#pragma unroll
    for (int i = 0; i < 4; ++i)
#pragma unroll
        for (int j = 0; j < 8; ++j) acc[i][j] = 0.0f;

    for (int kc = 0; kc < DD; kc += KC) {
#pragma unroll
        for (int it = 0; it < 2; ++it) {
            int idx = tid + it * 256;   // 0..511
            int r = idx >> 3, kq = idx & 7;
            int gr = row0 + r;
            float4 v = make_float4(0.f, 0.f, 0.f, 0.f);
            if (gr < M) v = *(const float4*)&x[gr * DD + kc + kq * 4];
            Xs[kq * 4 + 0][r] = v.x; Xs[kq * 4 + 1][r] = v.y;
            Xs[kq * 4 + 2][r] = v.z; Xs[kq * 4 + 3][r] = v.w;
        }
#pragma unroll
        for (int it = 0; it < 4; ++it) {
            int idx = tid + it * 256;   // 0..1023
            int o = idx >> 3, kq = idx & 7;
            float4 v = *(const float4*)&W[o * DD + kc + kq * 4];
            Ws[kq * 4 + 0][o] = v.x; Ws[kq * 4 + 1][o] = v.y;
            Ws[kq * 4 + 2][o] = v.z; Ws[kq * 4 + 3][o] = v.w;
        }
        __syncthreads();

#pragma unroll 8
        for (int k = 0; k < KC; ++k) {
            float4 xv = *(const float4*)&Xs[k][rg * 4];
            float4 w0 = *(const float4*)&Ws[k][cg_ * 8];
            float4 w1 = *(const float4*)&Ws[k][cg_ * 8 + 4];
            float xr[4] = {xv.x, xv.y, xv.z, xv.w};
            float wc[8] = {w0.x, w0.y, w0.z, w0.w, w1.x, w1.y, w1.z, w1.w};
#pragma unroll
            for (int i = 0; i < 4; ++i)
#pragma unroll
                for (int j = 0; j < 8; ++j) acc[i][j] += xr[i] * wc[j];
        }
        __syncthreads();
    }

    float4 b0 = *(const float4*)&b[cg_ * 8];
    float4 b1 = *(const float4*)&b[cg_ * 8 + 4];
    float bb[8] = {b0.x, b0.y, b0.z, b0.w, b1.x, b1.y, b1.z, b1.w};
#pragma unroll
    for (int i = 0; i < 4; ++i) {
        int gr = row0 + rg * 4 + i;
        if (gr < M) {
            float v[8];
#pragma unroll
            for (int j = 0; j < 8; ++j) v[j] = acc[i][j] + bb[j];
            *(float4*)&xt[gr * DD + cg_ * 8]     = make_float4(v[0], v[1], v[2], v[3]);
            *(float4*)&xt[gr * DD + cg_ * 8 + 4] = make_float4(v[4], v[5], v[6], v[7]);
            uint4 p;
            p.x = f2bf_rne(v[0]) | (f2bf_rne(v[1]) << 16);
            p.y = f2bf_rne(v[2]) | (f2bf_rne(v[3]) << 16);
            p.z = f2bf_rne(v[4]) | (f2bf_rne(v[5]) << 16);
            p.w = f2bf_rne(v[6]) | (f2bf_rne(v[7]) << 16);
            unsigned* xp = xtb + (size_t)(cg_ >> 3) * ((size_t)PS * 32)
                               + (size_t)gr * 32 + ((cg_ & 7) << 2);
            *(uint4*)xp = p;
        }
    }
}

__global__ __launch_bounds__(256) void gemm_xwT(const float* x,
                                                const float* __restrict__ W,
                                                const float* __restrict__ b,
                                                float* xt,
                                                unsigned* __restrict__ xtb, int M, int PS) {
    __shared__ float Xs[KC][MT + 4];
    __shared__ float Ws[KC][DD + 4];
    gemm_body(Xs, Ws, x, W, b, xt, xtb, M, PS, blockIdx.x);
}

// Fused: blocks [0,PA) = Phase-A edge binning (LDS histogram -> few global
// atomics -> semi-coalesced bucket-store writes); blocks [PA,PA+GB) = GEMM-1.
__global__ __launch_bounds__(256) void gemm1_plus_binA(const float* x,
                                                       const float* __restrict__ W,
                                                       const float* __restrict__ b,
                                                       float* xt,
                                                       unsigned* __restrict__ xtb, int M, int PS,
                                                       const int* __restrict__ src,
                                                       const int* __restrict__ dst,
                                                       int* __restrict__ bucket_count,
                                                       unsigned* __restrict__ bstore,
                                                       int E, int NB, int PA) {
    __shared__ float Xs[KC][MT + 4];
    __shared__ float Ws[KC][DD + 4];
    __shared__ int hist[NBMAX];
    __shared__ int basec[NBMAX];
    __shared__ int cur[NBMAX];

    if ((int)blockIdx.x >= PA) {
        gemm_body(Xs, Ws, x, W, b, xt, xtb, M, PS, blockIdx.x - PA);
        return;
    }

    const int tid = threadIdx.x;
    for (int i = tid; i < NB; i += 256) hist[i] = 0;
    __syncthreads();

    // load 16 edges/thread (4 rounds of coalesced int4)
    int dv[16], sv[16];
    const int ebase = blockIdx.x * AEPW;
#pragma unroll
    for (int r = 0; r < 4; ++r) {
        int e = ebase + r * 1024 + tid * 4;
        if (e + 4 <= E) {
            int4 d4 = *(const int4*)&dst[e];
            int4 s4 = *(const int4*)&src[e];
            dv[r*4+0] = d4.x; dv[r*4+1] = d4.y; dv[r*4+2] = d4.z; dv[r*4+3] = d4.w;
            sv[r*4+0] = s4.x; sv[r*4+1] = s4.y; sv[r*4+2] = s4.z; sv[r*4+3] = s4.w;
        } else {
#pragma unroll
            for (int q = 0; q < 4; ++q) {
                int ee = e + q;
                if (ee < E) { dv[r*4+q] = dst[ee]; sv[r*4+q] = src[ee]; }
                else        { dv[r*4+q] = -1;      sv[r*4+q] = 0; }
            }
        }
    }
#pragma unroll
    for (int i = 0; i < 16; ++i)
        if (dv[i] >= 0) atomicAdd(&hist[dv[i] >> 6], 1);
    __syncthreads();

    for (int bk = tid; bk < NB; bk += 256) {
        int h = hist[bk];
        basec[bk] = h ? atomicAdd(&bucket_count[bk], h) : 0;
        cur[bk] = 0;
    }
    __syncthreads();

#pragma unroll
    for (int i = 0; i < 16; ++i) {
        if (dv[i] >= 0) {
            int bk = dv[i] >> 6;
            int pos = basec[bk] + atomicAdd(&cur[bk], 1);
            if (pos < ACAP)
                bstore[bk * ACAP + pos] = ((unsigned)(dv[i] & 63) << 16) | (unsigned)sv[i];
        }
    }
}

// Phase B: one workgroup per bucket. Slot assignment via LDS atomics; colell
// writes stay in a private 16KB region. Emits deg, pads each ELL row to a
// multiple of 4 edges with sentinel index N (the all-zero bf16 row), and
// block 0 writes the zero sentinel rows themselves.
__global__ __launch_bounds__(256) void ell_build(const unsigned* __restrict__ bstore,
                                                 const int* __restrict__ bucket_count,
                                                 unsigned short* __restrict__ colell,
                                                 int* __restrict__ deg,
                                                 unsigned* __restrict__ xtb,
                                                 int PS, int N) {
    __shared__ int c64[64];
    const int bk = blockIdx.x;
    for (int i = threadIdx.x; i < 64; i += 256) c64[i] = 0;
    __syncthreads();
    int cnt = bucket_count[bk];
    if (cnt > ACAP) cnt = ACAP;
    for (int i = threadIdx.x; i < cnt; i += 256) {
        unsigned code = bstore[bk * ACAP + i];
        int local = (int)(code >> 16);
        int s     = (int)(code & 0xffffu);
        int p = atomicAdd(&c64[local], 1);
        if (p < ELLC)
            colell[((((bk << 6) + local)) << 7) + p] = (unsigned short)s;
    }
    __syncthreads();
    if (threadIdx.x < 64) {
        int node = (bk << 6) + threadIdx.x;
        if (node < N) {
            int d = c64[threadIdx.x];
            deg[node] = d;
            int stored = d < ELLC ? d : ELLC;
            int padded = (stored + 3) & ~3;          // pad to 4-edge quads
            if (padded > ELLC) padded = ELLC;
            unsigned short* row = colell + ((size_t)node << 7);
            for (int p2 = stored; p2 < padded; ++p2) row[p2] = (unsigned short)N;
        }
    }
    if (bk == 0 && threadIdx.x >= 64 && threadIdx.x < 80) {
        int i  = threadIdx.x - 64;      // 0..15
        int pl = i >> 3;                // plane
        int j  = i & 7;                 // uint4 index within row
        *(uint4*)&xtb[((size_t)pl * PS + (size_t)N) * 32 + (size_t)j * 4] =
            make_uint4(0u, 0u, 0u, 0u);
    }
}

// ---------------- fused aggregate ----------------
// out[n,f] = relu( (sum_e bf16(xt[col[e],f])) / deg[n] ) + xt[n,f]
// ONE 64-lane wave per node, covering BOTH 64-feature planes interleaved:
// one deg load + one crow load + one shfl chain feeds TWO gathers per
// edge-quad (plane-0 and plane-1 rows). 16 loads in flight per wave.
// Lanes: h=lane&15 carries features 4h..4h+3 of each plane, q=lane>>4 carries
// edge slot -> each uint2 gather instr fetches FOUR edges' 128-B plane rows.
// ELL rows padded to multiples of 4 edges with sentinel N (zero row), so the
// quad loop is branch-free with compile-time register indexing.
// xt/out alias (in-place residual): each wave reads only its own node's row.
__global__ __launch_bounds__(256) void gcn_aggregate(const uint2* __restrict__ xtb2,
                                                     const float* xt,
                                                     const unsigned short* __restrict__ colell,
                                                     const int* __restrict__ deg,
                                                     float* out, int PS, int N) {
    const int wave = threadIdx.x >> 6;
    const int lane = threadIdx.x & 63;
    const int node = (int)blockIdx.x * 4 + wave;
    if (node >= N) return;
    const int h = lane & 15;        // feature-quad: features 4h..4h+3 of each plane
    const int q = lane >> 4;        // edge slot 0..3

    const uint2* __restrict__ xl0 = xtb2 + h;                        // plane 0
    const uint2* __restrict__ xl1 = xtb2 + ((size_t)PS << 4) + h;    // plane 1
    const unsigned short* __restrict__ crow = colell + ((size_t)node << 7);
    const int cnt = deg[node];                        // wave-uniform (true degree)
    const int cl  = cnt < ELLC ? cnt : ELLC;          // stored edges

    float a0 = 0.f, a1 = 0.f, a2 = 0.f, a3 = 0.f;
    float a4 = 0.f, a5 = 0.f, a6 = 0.f, a7 = 0.f;

#define GATH2(j_) { int s_ = __shfl(myidx, ((t + (j_)) << 2) | q, 64); \
                    u0[j_] = xl0[(size_t)s_ << 4]; \
                    u1[j_] = xl1[(size_t)s_ << 4]; }
#define UNPK2(j_) { a0 += __uint_as_float(u0[j_].x << 16); \
                    a1 += __uint_as_float(u0[j_].x & 0xffff0000u); \
                    a2 += __uint_as_float(u0[j_].y << 16); \
                    a3 += __uint_as_float(u0[j_].y & 0xffff0000u); \
                    a4 += __uint_as_float(u1[j_].x << 16); \
                    a5 += __uint_as_float(u1[j_].x & 0xffff0000u); \
                    a6 += __uint_as_float(u1[j_].y << 16); \
                    a7 += __uint_as_float(u1[j_].y & 0xffff0000u); }

    for (int base = 0; base < cl; base += 64) {
        const int rem = cl - base;
        const int c = rem < 64 ? rem : 64;
        const int myidx = (int)crow[base + lane];     // coalesced ushort (padded rows)
        const int cq = (c + 3) >> 2;                  // 4-edge quads (row padded to 4)
        int t = 0;
        for (; t + 8 <= cq; t += 8) {                 // flight of 16 instrs = 32 edges
            uint2 u0[8], u1[8];
            GATH2(0) GATH2(1) GATH2(2) GATH2(3)
            GATH2(4) GATH2(5) GATH2(6) GATH2(7)
            UNPK2(0) UNPK2(1) UNPK2(2) UNPK2(3)
            UNPK2(4) UNPK2(5) UNPK2(6) UNPK2(7)
        }
        for (; t < cq; ++t) {                         // tail quads (2 instrs = 4 edges)
            uint2 u0[1], u1[1];
            GATH2(0)
            UNPK2(0)
        }
    }
#undef GATH2
#undef UNPK2

    // merge the 4 edge-slot streams into lanes 0-15 (q==0)
    a0 += __shfl_down(a0, 32, 64); a1 += __shfl_down(a1, 32, 64);
    a2 += __shfl_down(a2, 32, 64); a3 += __shfl_down(a3, 32, 64);
    a4 += __shfl_down(a4, 32, 64); a5 += __shfl_down(a5, 32, 64);
    a6 += __shfl_down(a6, 32, 64); a7 += __shfl_down(a7, 32, 64);
    a0 += __shfl_down(a0, 16, 64); a1 += __shfl_down(a1, 16, 64);
    a2 += __shfl_down(a2, 16, 64); a3 += __shfl_down(a3, 16, 64);
    a4 += __shfl_down(a4, 16, 64); a5 += __shfl_down(a5, 16, 64);
    a6 += __shfl_down(a6, 16, 64); a7 += __shfl_down(a7, 16, 64);

    if (q == 0) {
        const float di = (cnt > 0) ? (1.0f / (float)cnt) : 0.0f;
        float4 tA = ((const float4*)xt)[(size_t)node * 32 + h];        // feats 4h..4h+3
        float4 tB = ((const float4*)xt)[(size_t)node * 32 + 16 + h];   // feats 64+4h..
        float4 oA, oB;
        oA.x = fmaxf(a0 * di, 0.f) + tA.x;
        oA.y = fmaxf(a1 * di, 0.f) + tA.y;
        oA.z = fmaxf(a2 * di, 0.f) + tA.z;
        oA.w = fmaxf(a3 * di, 0.f) + tA.w;
        oB.x = fmaxf(a4 * di, 0.f) + tB.x;
        oB.y = fmaxf(a5 * di, 0.f) + tB.y;
        oB.z = fmaxf(a6 * di, 0.f) + tB.z;
        oB.w = fmaxf(a7 * di, 0.f) + tB.w;
        ((float4*)out)[(size_t)node * 32 + h]      = oA;
        ((float4*)out)[(size_t)node * 32 + 16 + h] = oB;
    }
}

extern "C" void kernel_launch(void* const* d_in, const int* in_sizes, int n_in,
                              void* d_out, int out_size, void* d_ws, size_t ws_size,
                              hipStream_t stream) {
    const float* x  = (const float*)d_in[0];
    const int*   ei = (const int*)d_in[1];      // [2, E] int32
    const float* W1 = (const float*)d_in[2];
    const float* b1 = (const float*)d_in[3];
    const float* W2 = (const float*)d_in[4];
    const float* b2 = (const float*)d_in[5];
    const float* W3 = (const float*)d_in[6];
    const float* b3 = (const float*)d_in[7];

    const int N  = in_sizes[0] / DD;     // 20000
    const int E  = in_sizes[1] / 2;      // 640000
    const int PS = N + 1;                // plane row count (incl. zero sentinel row)

    const int* src = ei;
    const int* dst = ei + E;

    const int NB = (N + 63) >> 6;            // 313 buckets
    const int PA = (E + AEPW - 1) / AEPW;    // 157 phase-A blocks
    const int GB = (N + MT - 1) / MT;        // 313 gemm blocks
    const int AB = (N + 3) / 4;              // aggregate blocks (4 nodes/block)

    // workspace layout (256B-aligned offsets) — ~13.2 MB total
    char* ws = (char*)d_ws;
    size_t off = 0;
    auto alloc = [&](size_t bytes) {
        void* p = ws + off;
        off += (bytes + 255) & ~(size_t)255;
        return p;
    };
    int*            bucket_count = (int*)alloc((size_t)NB * sizeof(int));
    unsigned*       bstore       = (unsigned*)alloc((size_t)NB * ACAP * sizeof(unsigned));
    unsigned short* colell       = (unsigned short*)alloc((size_t)NB * 64 * ELLC * sizeof(unsigned short));
    int*            deg          = (int*)alloc((size_t)N * sizeof(int));
    unsigned*       xtb          = (unsigned*)alloc((size_t)PS * 256);   // 2 planes x PS x 128 B

    float* xbuf = (float*)d_out;  // fp32 xt lives in d_out (in-place per layer)

    hipMemsetAsync(bucket_count, 0, (size_t)NB * sizeof(int), stream);
    // K1: Phase-A binning + layer-1 GEMM (x -> xbuf fp32 + xtb bf16 planes)
    gemm1_plus_binA<<<PA + GB, 256, 0, stream>>>(x, W1, b1, xbuf, xtb, N, PS,
                                                 src, dst, bucket_count, bstore, E, NB, PA);
    // K2: Phase-B ELL build + deg + padding + zero sentinel rows
    ell_build<<<NB, 256, 0, stream>>>(bstore, bucket_count, colell, deg, xtb, PS, N);

    gcn_aggregate<<<AB, 256, 0, stream>>>((const uint2*)xtb, xbuf, colell, deg, xbuf, PS, N);

    gemm_xwT<<<GB, 256, 0, stream>>>(xbuf, W2, b2, xbuf, xtb, N, PS);
    gcn_aggregate<<<AB, 256, 0, stream>>>((const uint2*)xtb, xbuf, colell, deg, xbuf, PS, N);

    gemm_xwT<<<GB, 256, 0, stream>>>(xbuf, W3, b3, xbuf, xtb, N, PS);
    gcn_aggregate<<<AB, 256, 0, stream>>>((const uint2*)xtb, xbuf, colell, deg, xbuf, PS, N);
}

// Round 5
// 207.385 us; speedup vs baseline: 7.2407x; 1.0934x over previous
//
#include <hip/hip_runtime.h>

#define DD 128          // feature dim
#define KC 32           // k-chunk in gemm
#define MT 64           // rows per block in gemm
#define ELLC 128        // ELL row slots (124 index slots + pad + deg in slot 127)
#define ELLI 124        // max stored indices per row (deg ~ Poisson(32), max ~65)
#define NBMAX 320       // max dst-buckets (64 nodes each)
#define ACAP 2304       // bucket capacity: mean 2045, sigma ~45 -> +5.7 sigma
#define AEPW 4096       // edges per phase-A workgroup
#define AGGB 2048       // aggregate blocks (persistent waves, 8 blocks/CU)

__device__ __forceinline__ unsigned f2bf_rne(float f) {
    unsigned u = __float_as_uint(f);
    u += 0x7fffu + ((u >> 16) & 1u);
    return u >> 16;
}

// ---------------- GEMM body ----------------
// xt = x @ W.T + b (fp32, possibly IN-PLACE on x: each block reads only its own
// 64 rows and writes them in the epilogue after all k-chunks are consumed),
// plus packed-bf16 copy xtb laid out as TWO 64-feature planes of (PS=N+1) rows
// x 128 B each (row N of each plane is a permanently-zero sentinel row used by
// ELL padding).
// NOTE: x/xt deliberately NOT __restrict__ (they alias for layers 2,3).
__device__ __forceinline__ void gemm_body(float (*Xs)[MT + 4], float (*Ws)[DD + 4],
                                          const float* x,
                                          const float* __restrict__ W,
                                          const float* __restrict__ b,
                                          float* xt,
                                          unsigned* __restrict__ xtb, int M, int PS, int blk) {
    const int tid  = threadIdx.x;       // 0..255
    const int cg_  = tid & 15;          // cols cg*8 .. cg*8+7
    const int rg   = tid >> 4;          // rows rg*4 .. rg*4+3
    const int row0 = blk * MT;

    float acc[4][8];
#pragma unroll
    for (int i = 0; i < 4; ++i)
#pragma unroll
        for (int j = 0; j < 8; ++j) acc[i][j] = 0.0f;

    for (int kc = 0; kc < DD; kc += KC) {
#pragma unroll
        for (int it = 0; it < 2; ++it) {
            int idx = tid + it * 256;   // 0..511
            int r = idx >> 3, kq = idx & 7;
            int gr = row0 + r;
            float4 v = make_float4(0.f, 0.f, 0.f, 0.f);
            if (gr < M) v = *(const float4*)&x[gr * DD + kc + kq * 4];
            Xs[kq * 4 + 0][r] = v.x; Xs[kq * 4 + 1][r] = v.y;
            Xs[kq * 4 + 2][r] = v.z; Xs[kq * 4 + 3][r] = v.w;
        }
#pragma unroll
        for (int it = 0; it < 4; ++it) {
            int idx = tid + it * 256;   // 0..1023
            int o = idx >> 3, kq = idx & 7;
            float4 v = *(const float4*)&W[o * DD + kc + kq * 4];
            Ws[kq * 4 + 0][o] = v.x; Ws[kq * 4 + 1][o] = v.y;
            Ws[kq * 4 + 2][o] = v.z; Ws[kq * 4 + 3][o] = v.w;
        }
        __syncthreads();

#pragma unroll 8
        for (int k = 0; k < KC; ++k) {
            float4 xv = *(const float4*)&Xs[k][rg * 4];
            float4 w0 = *(const float4*)&Ws[k][cg_ * 8];
            float4 w1 = *(const float4*)&Ws[k][cg_ * 8 + 4];
            float xr[4] = {xv.x, xv.y, xv.z, xv.w};
            float wc[8] = {w0.x, w0.y, w0.z, w0.w, w1.x, w1.y, w1.z, w1.w};
#pragma unroll
            for (int i = 0; i < 4; ++i)
#pragma unroll
                for (int j = 0; j < 8; ++j) acc[i][j] += xr[i] * wc[j];
        }
        __syncthreads();
    }

    float4 b0 = *(const float4*)&b[cg_ * 8];
    float4 b1 = *(const float4*)&b[cg_ * 8 + 4];
    float bb[8] = {b0.x, b0.y, b0.z, b0.w, b1.x, b1.y, b1.z, b1.w};
#pragma unroll
    for (int i = 0; i < 4; ++i) {
        int gr = row0 + rg * 4 + i;
        if (gr < M) {
            float v[8];
#pragma unroll
            for (int j = 0; j < 8; ++j) v[j] = acc[i][j] + bb[j];
            *(float4*)&xt[gr * DD + cg_ * 8]     = make_float4(v[0], v[1], v[2], v[3]);
            *(float4*)&xt[gr * DD + cg_ * 8 + 4] = make_float4(v[4], v[5], v[6], v[7]);
            uint4 p;
            p.x = f2bf_rne(v[0]) | (f2bf_rne(v[1]) << 16);
            p.y = f2bf_rne(v[2]) | (f2bf_rne(v[3]) << 16);
            p.z = f2bf_rne(v[4]) | (f2bf_rne(v[5]) << 16);
            p.w = f2bf_rne(v[6]) | (f2bf_rne(v[7]) << 16);
            unsigned* xp = xtb + (size_t)(cg_ >> 3) * ((size_t)PS * 32)
                               + (size_t)gr * 32 + ((cg_ & 7) << 2);
            *(uint4*)xp = p;
        }
    }
}

__global__ __launch_bounds__(256) void gemm_xwT(const float* x,
                                                const float* __restrict__ W,
                                                const float* __restrict__ b,
                                                float* xt,
                                                unsigned* __restrict__ xtb, int M, int PS) {
    __shared__ float Xs[KC][MT + 4];
    __shared__ float Ws[KC][DD + 4];
    gemm_body(Xs, Ws, x, W, b, xt, xtb, M, PS, blockIdx.x);
}

// Fused: blocks [0,PA) = Phase-A edge binning (LDS histogram -> few global
// atomics -> semi-coalesced bucket-store writes); blocks [PA,PA+GB) = GEMM-1.
__global__ __launch_bounds__(256) void gemm1_plus_binA(const float* x,
                                                       const float* __restrict__ W,
                                                       const float* __restrict__ b,
                                                       float* xt,
                                                       unsigned* __restrict__ xtb, int M, int PS,
                                                       const int* __restrict__ src,
                                                       const int* __restrict__ dst,
                                                       int* __restrict__ bucket_count,
                                                       unsigned* __restrict__ bstore,
                                                       int E, int NB, int PA) {
    __shared__ float Xs[KC][MT + 4];
    __shared__ float Ws[KC][DD + 4];
    __shared__ int hist[NBMAX];
    __shared__ int basec[NBMAX];
    __shared__ int cur[NBMAX];

    if ((int)blockIdx.x >= PA) {
        gemm_body(Xs, Ws, x, W, b, xt, xtb, M, PS, blockIdx.x - PA);
        return;
    }

    const int tid = threadIdx.x;
    for (int i = tid; i < NB; i += 256) hist[i] = 0;
    __syncthreads();

    // load 16 edges/thread (4 rounds of coalesced int4)
    int dv[16], sv[16];
    const int ebase = blockIdx.x * AEPW;
#pragma unroll
    for (int r = 0; r < 4; ++r) {
        int e = ebase + r * 1024 + tid * 4;
        if (e + 4 <= E) {
            int4 d4 = *(const int4*)&dst[e];
            int4 s4 = *(const int4*)&src[e];
            dv[r*4+0] = d4.x; dv[r*4+1] = d4.y; dv[r*4+2] = d4.z; dv[r*4+3] = d4.w;
            sv[r*4+0] = s4.x; sv[r*4+1] = s4.y; sv[r*4+2] = s4.z; sv[r*4+3] = s4.w;
        } else {
#pragma unroll
            for (int q = 0; q < 4; ++q) {
                int ee = e + q;
                if (ee < E) { dv[r*4+q] = dst[ee]; sv[r*4+q] = src[ee]; }
                else        { dv[r*4+q] = -1;      sv[r*4+q] = 0; }
            }
        }
    }
#pragma unroll
    for (int i = 0; i < 16; ++i)
        if (dv[i] >= 0) atomicAdd(&hist[dv[i] >> 6], 1);
    __syncthreads();

    for (int bk = tid; bk < NB; bk += 256) {
        int h = hist[bk];
        basec[bk] = h ? atomicAdd(&bucket_count[bk], h) : 0;
        cur[bk] = 0;
    }
    __syncthreads();

#pragma unroll
    for (int i = 0; i < 16; ++i) {
        if (dv[i] >= 0) {
            int bk = dv[i] >> 6;
            int pos = basec[bk] + atomicAdd(&cur[bk], 1);
            if (pos < ACAP)
                bstore[bk * ACAP + pos] = ((unsigned)(dv[i] & 63) << 16) | (unsigned)sv[i];
        }
    }
}

// Phase B: one workgroup per bucket. Slot assignment via LDS atomics; colell
// writes stay in a private 16KB region. Each node's 256-B row: slots 0..123 =
// src indices (padded to a multiple of 4 with sentinel N = zero row), slot 127
// = degree (so the aggregate reads indices+deg in ONE uint/lane load).
// Block 0 also writes the zero sentinel rows of both bf16 planes.
__global__ __launch_bounds__(256) void ell_build(const unsigned* __restrict__ bstore,
                                                 const int* __restrict__ bucket_count,
                                                 unsigned short* __restrict__ colell,
                                                 unsigned* __restrict__ xtb,
                                                 int PS, int N) {
    __shared__ int c64[64];
    const int bk = blockIdx.x;
    for (int i = threadIdx.x; i < 64; i += 256) c64[i] = 0;
    __syncthreads();
    int cnt = bucket_count[bk];
    if (cnt > ACAP) cnt = ACAP;
    for (int i = threadIdx.x; i < cnt; i += 256) {
        unsigned code = bstore[bk * ACAP + i];
        int local = (int)(code >> 16);
        int s     = (int)(code & 0xffffu);
        int p = atomicAdd(&c64[local], 1);
        if (p < ELLI)
            colell[((((bk << 6) + local)) << 7) + p] = (unsigned short)s;
    }
    __syncthreads();
    if (threadIdx.x < 64) {
        int node = (bk << 6) + threadIdx.x;
        if (node < N) {
            int d = c64[threadIdx.x];
            int stored = d < ELLI ? d : ELLI;
            int padded = (stored + 3) & ~3;          // pad to 4-edge quads (<=124)
            unsigned short* row = colell + ((size_t)node << 7);
            for (int p2 = stored; p2 < padded; ++p2) row[p2] = (unsigned short)N;
            row[127] = (unsigned short)(d < 65535 ? d : 65535);   // deg in slot 127
        }
    }
    if (bk == 0 && threadIdx.x >= 64 && threadIdx.x < 80) {
        int i  = threadIdx.x - 64;      // 0..15
        int pl = i >> 3;                // plane
        int j  = i & 7;                 // uint4 index within row
        *(uint4*)&xtb[((size_t)pl * PS + (size_t)N) * 32 + (size_t)j * 4] =
            make_uint4(0u, 0u, 0u, 0u);
    }
}

// ---------------- fused aggregate ----------------
// out[n,f] = relu( (sum_e bf16(xt[col[e],f])) / deg[n] ) + xt[n,f]
// Persistent waves, one (node,plane) task at a time, ~5 tasks/wave.
// Per task: ONE uint/lane load brings the whole colell row (124 index slots +
// deg in slot 127). The NEXT task's row load is issued right after the current
// task's first gather flight, so its HBM latency hides under unpack/reduce.
// Lanes: h=lane&15 carries features 4h..4h+3 of the plane, q=lane>>4 carries
// edge slot -> each uint2 gather instr fetches FOUR edges' 128-B plane rows.
// xt/out alias (in-place residual): each task touches only its own node's row.
__global__ __launch_bounds__(256, 8) void gcn_aggregate(const uint2* __restrict__ xtb2,
                                                        const float* xt,
                                                        const unsigned* __restrict__ colell32,
                                                        float* out, int PS, int N) {
    const int lane = threadIdx.x & 63;
    const int wid  = (int)blockIdx.x * 4 + (threadIdx.x >> 6);
    const int NW   = (int)gridDim.x * 4;
    const int T    = 2 * N;
    if (wid >= T) return;
    const int h = lane & 15;        // feature-quad: features 4h..4h+3 of the plane
    const int q = lane >> 4;        // edge slot 0..3

    // first task's packed colell row (slots 2*lane, 2*lane+1)
    int t = wid;
    int node0 = (t >= N) ? t - N : t;
    unsigned pk = colell32[((size_t)node0 << 6) + lane];

    while (t < T) {
        const int tn    = t + NW;
        const int node  = (t >= N) ? t - N : t;
        const int plane = (t >= N) ? 1 : 0;
        const uint2* __restrict__ xl = xtb2 + (size_t)plane * ((size_t)PS << 4) + h;

        const unsigned w63 = __shfl(pk, 63, 64);
        const int cnt = (int)(w63 >> 16);               // true degree (slot 127)
        const int cl  = cnt < ELLI ? cnt : ELLI;
        const int cq  = (cl + 3) >> 2;                  // 4-edge quads (padded)

        // residual read in flight during the gathers (q==0 lanes only)
        float4 t4 = make_float4(0.f, 0.f, 0.f, 0.f);
        if (q == 0)
            t4 = ((const float4*)xt)[(size_t)node * 32 + plane * 16 + h];

        float a0 = 0.f, a1 = 0.f, a2 = 0.f, a3 = 0.f;
        unsigned pkn = 0;
        bool first = true;

        int tq = 0;
        while (tq < cq) {
            int f = cq - tq; if (f > 8) f = 8;
            uint2 u[8];
#pragma unroll
            for (int j = 0; j < 8; ++j) if (j < f) {
                int e = ((tq + j) << 2) | q;            // edge slot 0..123
                unsigned w = __shfl(pk, e >> 1, 64);
                int s = (e & 1) ? (int)(w >> 16) : (int)(w & 0xffffu);
                u[j] = xl[(size_t)s << 4];
            }
            if (first) {                                 // prefetch next task's row
                if (tn < T) {
                    int nnode = (tn >= N) ? tn - N : tn;
                    pkn = colell32[((size_t)nnode << 6) + lane];
                }
                first = false;
            }
#pragma unroll
            for (int j = 0; j < 8; ++j) if (j < f) {
                a0 += __uint_as_float(u[j].x << 16);
                a1 += __uint_as_float(u[j].x & 0xffff0000u);
                a2 += __uint_as_float(u[j].y << 16);
                a3 += __uint_as_float(u[j].y & 0xffff0000u);
            }
            tq += f;
        }
        if (first && tn < T) {                           // deg==0 path still prefetches
            int nnode = (tn >= N) ? tn - N : tn;
            pkn = colell32[((size_t)nnode << 6) + lane];
        }

        // merge the 4 edge-slot streams into lanes 0-15
        a0 += __shfl_down(a0, 32, 64); a1 += __shfl_down(a1, 32, 64);
        a2 += __shfl_down(a2, 32, 64); a3 += __shfl_down(a3, 32, 64);
        a0 += __shfl_down(a0, 16, 64); a1 += __shfl_down(a1, 16, 64);
        a2 += __shfl_down(a2, 16, 64); a3 += __shfl_down(a3, 16, 64);

        if (q == 0) {
            const float di = (cnt > 0) ? (1.0f / (float)cnt) : 0.0f;
            float4 o;
            o.x = fmaxf(a0 * di, 0.f) + t4.x;
            o.y = fmaxf(a1 * di, 0.f) + t4.y;
            o.z = fmaxf(a2 * di, 0.f) + t4.z;
            o.w = fmaxf(a3 * di, 0.f) + t4.w;
            ((float4*)out)[(size_t)node * 32 + plane * 16 + h] = o;
        }

        t = tn;
        pk = pkn;
    }
}

extern "C" void kernel_launch(void* const* d_in, const int* in_sizes, int n_in,
                              void* d_out, int out_size, void* d_ws, size_t ws_size,
                              hipStream_t stream) {
    const float* x  = (const float*)d_in[0];
    const int*   ei = (const int*)d_in[1];      // [2, E] int32
    const float* W1 = (const float*)d_in[2];
    const float* b1 = (const float*)d_in[3];
    const float* W2 = (const float*)d_in[4];
    const float* b2 = (const float*)d_in[5];
    const float* W3 = (const float*)d_in[6];
    const float* b3 = (const float*)d_in[7];

    const int N  = in_sizes[0] / DD;     // 20000
    const int E  = in_sizes[1] / 2;      // 640000
    const int PS = N + 1;                // plane row count (incl. zero sentinel row)

    const int* src = ei;
    const int* dst = ei + E;

    const int NB = (N + 63) >> 6;            // 313 buckets
    const int PA = (E + AEPW - 1) / AEPW;    // 157 phase-A blocks
    const int GB = (N + MT - 1) / MT;        // 313 gemm blocks

    // workspace layout (256B-aligned offsets) — ~13.2 MB total
    char* ws = (char*)d_ws;
    size_t off = 0;
    auto alloc = [&](size_t bytes) {
        void* p = ws + off;
        off += (bytes + 255) & ~(size_t)255;
        return p;
    };
    int*            bucket_count = (int*)alloc((size_t)NB * sizeof(int));
    unsigned*       bstore       = (unsigned*)alloc((size_t)NB * ACAP * sizeof(unsigned));
    unsigned short* colell       = (unsigned short*)alloc((size_t)NB * 64 * ELLC * sizeof(unsigned short));
    unsigned*       xtb          = (unsigned*)alloc((size_t)PS * 256);   // 2 planes x PS x 128 B

    float* xbuf = (float*)d_out;  // fp32 xt lives in d_out (in-place per layer)

    hipMemsetAsync(bucket_count, 0, (size_t)NB * sizeof(int), stream);
    // K1: Phase-A binning + layer-1 GEMM (x -> xbuf fp32 + xtb bf16 planes)
    gemm1_plus_binA<<<PA + GB, 256, 0, stream>>>(x, W1, b1, xbuf, xtb, N, PS,
                                                 src, dst, bucket_count, bstore, E, NB, PA);
    // K2: Phase-B ELL build (indices + deg-in-row) + zero sentinel rows
    ell_build<<<NB, 256, 0, stream>>>(bstore, bucket_count, colell, xtb, PS, N);

    gcn_aggregate<<<AGGB, 256, 0, stream>>>((const uint2*)xtb, xbuf,
                                            (const unsigned*)colell, xbuf, PS, N);

    gemm_xwT<<<GB, 256, 0, stream>>>(xbuf, W2, b2, xbuf, xtb, N, PS);
    gcn_aggregate<<<AGGB, 256, 0, stream>>>((const uint2*)xtb, xbuf,
                                            (const unsigned*)colell, xbuf, PS, N);

    gemm_xwT<<<GB, 256, 0, stream>>>(xbuf, W3, b3, xbuf, xtb, N, PS);
    gcn_aggregate<<<AGGB, 256, 0, stream>>>((const uint2*)xtb, xbuf,
                                            (const unsigned*)colell, xbuf, PS, N);
}